// Round 1
// baseline (47.566 us; speedup 1.0000x reference)
//
#include <hip/hip_runtime.h>

// Problem constants (from reference): B=64, S=4096, D=256, LABELS=50
#define BB  64
#define SS  4096
#define DD  256
#define LBL 50

// Work decomposition for the segment-max:
//   NCHUNK blocks per batch, 4 waves per block -> WSLOTS = NCHUNK*4 wave-slots.
//   Wave-slot j of batch b handles the INTERLEAVED rows s = j, j+WSLOTS, ...
//   => every block of a batch does ~len/NCHUNK rows (perfect intra-batch
//   balance), unlike contiguous chunks where activity depends on len and the
//   dispatch round-robin pins chunk-index per CU (c = bid mod nchunk const
//   per CU -> c=0 CUs did ~2x mean work while high-c CUs idled).
#define NCHUNK 64
#define WSLOTS (NCHUNK * 4)   // 256 wave-slots per batch (S/WSLOTS = 16 rows/slot max)

typedef float f4 __attribute__((ext_vector_type(4)));

__device__ __forceinline__ f4 vmax4(f4 a, f4 b) {
    f4 r;
    r.x = fmaxf(a.x, b.x);
    r.y = fmaxf(a.y, b.y);
    r.z = fmaxf(a.z, b.z);
    r.w = fmaxf(a.w, b.w);
    return r;
}

// Kernel 1: per-(batch, slot-group) partial max over valid rows.
// Block = 256 threads = 4 waves. Wave w owns slot 4c+w; rows s = slot + k*WSLOTS.
// Each lane holds a float4 (16B) column slice -> one wave covers the full
// D=256 row per iteration, fully coalesced 1KB/row.
__global__ __launch_bounds__(256) void segmax_partial_kernel(
    const float* __restrict__ code,      // [B, S, D]
    const int*   __restrict__ lengths,   // [B]
    float*       __restrict__ partial)   // [B * NCHUNK, D]
{
    int bid = blockIdx.x;
    int b   = bid >> 6;                  // bid / NCHUNK
    int c   = bid & (NCHUNK - 1);
    int len = lengths[b];
    if (4 * c >= len) return;            // uniform per block: safe w.r.t. barrier

    int wave = threadIdx.x >> 6;
    int lane = threadIdx.x & 63;
    int slot = 4 * c + wave;             // 0..WSLOTS-1

    const f4* base = (const f4*)(code + (size_t)b * SS * DD) + lane;
    const float neg = -INFINITY;
    f4 m = (f4){neg, neg, neg, neg};

    // Strided rows: each iteration the 4 waves of this block read 4
    // consecutive rows (4KB contiguous), then jump WSLOTS rows ahead.
    for (int s = slot; s < len; s += WSLOTS) {
        f4 v = __builtin_nontemporal_load(base + (size_t)s * (DD / 4));
        m = vmax4(m, v);
    }

    __shared__ f4 red[4][64];
    red[wave][lane] = m;
    __syncthreads();

    if (threadIdx.x < 64) {
        f4 a = red[0][lane];
        #pragma unroll
        for (int w = 1; w < 4; ++w)
            a = vmax4(a, red[w][lane]);
        f4* dst = (f4*)(partial + (size_t)bid * DD);
        dst[lane] = a;
    }
}

// Kernel 2: per-batch final reduce over active partials + [256]x[256,50] dot.
__global__ __launch_bounds__(256) void finalize_kernel(
    const float* __restrict__ partial,   // [B * NCHUNK, D]
    const int*   __restrict__ lengths,   // [B]
    const float* __restrict__ Wp,        // [LBL, D] row-major
    float*       __restrict__ out)       // [B, LBL]
{
    int b = blockIdx.x;
    int t = threadIdx.x;                 // t = d index, 0..255
    int len  = lengths[b];
    // Block c wrote a partial iff 4c < len -> nact = ceil(len/4), capped.
    int nact = (len + 3) >> 2;
    if (nact > NCHUNK) nact = NCHUNK;

    float m = -INFINITY;
    const float* p = partial + (size_t)b * NCHUNK * DD + t;
    for (int c = 0; c < nact; ++c)
        m = fmaxf(m, p[(size_t)c * DD]);

    __shared__ float pool[DD];
    pool[t] = m;
    __syncthreads();

    if (t < LBL) {
        float acc = 0.0f;
        const float* w = Wp + (size_t)t * DD;
        #pragma unroll 8
        for (int d = 0; d < DD; ++d)
            acc += pool[d] * w[d];       // pool[d]: same addr all lanes -> LDS broadcast
        out[b * LBL + t] = acc;
    }
}

extern "C" void kernel_launch(void* const* d_in, const int* in_sizes, int n_in,
                              void* d_out, int out_size, void* d_ws, size_t ws_size,
                              hipStream_t stream) {
    // Input order (setup_inputs): 0 find_contri, 1 contri, 2 code_output,
    // 3 lengths, 4 hidden, 5 W_attn, 6 b_attn, 7 W_pool.
    // energy is dead compute in the reference -> hidden/W_attn/b_attn unused.
    const float* code    = (const float*)d_in[2];
    const int*   lengths = (const int*)  d_in[3];
    const float* Wp      = (const float*)d_in[7];
    float*       out     = (float*)d_out;
    float*       partial = (float*)d_ws;

    // Workspace need: 64 * 64 * 256 * 4B = 4 MB (ws observed ~1 GB).
    (void)ws_size;

    segmax_partial_kernel<<<BB * NCHUNK, 256, 0, stream>>>(code, lengths, partial);
    finalize_kernel<<<BB, 256, 0, stream>>>(partial, lengths, Wp, out);
}

// Round 2
// 33.750 us; speedup vs baseline: 1.4094x; 1.4094x over previous
//
#include <hip/hip_runtime.h>

// Problem constants (from reference): B=64, S=4096, D=256, LABELS=50
#define BB  64
#define SS  4096
#define DD  256
#define LBL 50

// 32 contiguous rows (32 KB) per chunk -> 128 chunks/batch, 8192 blocks.
// Only ~2048 blocks (8/CU, 32 waves) are resident; the other 6144 are
// dispatched ON-DEMAND by the hardware as blocks retire. That is the load
// balancer: round-0's 2048-block grid was FULLY resident (static placement,
// c = CU mod 32 pinned -> worst CU ~1 MB vs 0.5 MB mean -> ~36 us).
// Chunks stay contiguous (round-1's stride-256 interleave killed locality).
#define CROWS  32
#define NCHUNK (SS / CROWS)      // 128

typedef float f4 __attribute__((ext_vector_type(4)));

static __device__ __forceinline__ f4 vmax4(f4 a, f4 b) {
    f4 r;
    r.x = fmaxf(a.x, b.x);
    r.y = fmaxf(a.y, b.y);
    r.z = fmaxf(a.z, b.z);
    r.w = fmaxf(a.w, b.w);
    return r;
}

// Kernel 1: per-(batch, 32-row chunk) partial max over valid rows.
// Block = 256 threads = 4 waves. Wave w handles rows s0+w, s0+w+4, ... (8 rows
// when full). Each lane holds a float4 column slice -> one wave covers the
// full D=256 row per iteration, fully coalesced 1KB/row.
__global__ __launch_bounds__(256) void segmax_partial_kernel(
    const float* __restrict__ code,      // [B, S, D]
    const int*   __restrict__ lengths,   // [B]
    float*       __restrict__ partial)   // [B * NCHUNK, D]
{
    int bid = blockIdx.x;
    int b   = bid >> 7;                  // bid / NCHUNK
    int c   = bid & (NCHUNK - 1);
    int len = lengths[b];
    int s0  = c * CROWS;
    if (s0 >= len) return;               // uniform per block: safe w.r.t. barrier
    int s1 = min(s0 + CROWS, len);

    int wave = threadIdx.x >> 6;
    int lane = threadIdx.x & 63;

    const f4* p = (const f4*)(code + (size_t)b * SS * DD)
                + (size_t)(s0 + wave) * (DD / 4) + lane;
    const float neg = -INFINITY;
    f4 m = (f4){neg, neg, neg, neg};

    if (s1 - s0 == CROWS) {
        // Full chunk: 8 rows/wave. Issue all 8 loads before reducing (MLP=8).
        f4 v0 = p[0 * 256];
        f4 v1 = p[1 * 256];
        f4 v2 = p[2 * 256];
        f4 v3 = p[3 * 256];
        f4 v4 = p[4 * 256];
        f4 v5 = p[5 * 256];
        f4 v6 = p[6 * 256];
        f4 v7 = p[7 * 256];
        m = vmax4(vmax4(vmax4(v0, v1), vmax4(v2, v3)),
                  vmax4(vmax4(v4, v5), vmax4(v6, v7)));
    } else {
        // Boundary chunk (len cuts inside): generic strided loop.
        for (int s = s0 + wave; s < s1; s += 4, p += 4 * (DD / 4))
            m = vmax4(m, *p);
    }

    __shared__ f4 red[4][64];
    red[wave][lane] = m;
    __syncthreads();

    if (threadIdx.x < 64) {
        f4 a = red[0][lane];
        #pragma unroll
        for (int w = 1; w < 4; ++w)
            a = vmax4(a, red[w][lane]);
        f4* dst = (f4*)(partial + (size_t)bid * DD);
        dst[lane] = a;
    }
}

// Kernel 2: per-batch final reduce over active partials + [256]x[256,50] dot.
// Wave w strides chunks c = w, w+4, w+8, ... with 4-deep unroll for MLP.
__global__ __launch_bounds__(256) void finalize_kernel(
    const float* __restrict__ partial,   // [B * NCHUNK, D]
    const int*   __restrict__ lengths,   // [B]
    const float* __restrict__ Wp,        // [LBL, D] row-major
    float*       __restrict__ out)       // [B, LBL]
{
    int b    = blockIdx.x;
    int wave = threadIdx.x >> 6;
    int lane = threadIdx.x & 63;
    int len  = lengths[b];
    int nact = (len + CROWS - 1) / CROWS;          // chunks that wrote a partial
    if (nact > NCHUNK) nact = NCHUNK;

    const f4* pb = (const f4*)partial + (size_t)b * NCHUNK * (DD / 4) + lane;
    const float neg = -INFINITY;
    f4 m = (f4){neg, neg, neg, neg};

    int c = wave;
    for (; c + 12 < nact; c += 16) {               // 4 independent loads in flight
        f4 a0 = pb[(size_t)(c     ) * (DD / 4)];
        f4 a1 = pb[(size_t)(c +  4) * (DD / 4)];
        f4 a2 = pb[(size_t)(c +  8) * (DD / 4)];
        f4 a3 = pb[(size_t)(c + 12) * (DD / 4)];
        m = vmax4(m, vmax4(vmax4(a0, a1), vmax4(a2, a3)));
    }
    for (; c < nact; c += 4)
        m = vmax4(m, pb[(size_t)c * (DD / 4)]);

    __shared__ f4 red[4][64];
    __shared__ float pool[DD];
    red[wave][lane] = m;
    __syncthreads();

    if (threadIdx.x < 64) {
        f4 a = red[0][lane];
        #pragma unroll
        for (int w = 1; w < 4; ++w)
            a = vmax4(a, red[w][lane]);
        ((f4*)pool)[lane] = a;
    }
    __syncthreads();

    if (threadIdx.x < LBL) {
        float acc = 0.0f;
        const float* w = Wp + (size_t)threadIdx.x * DD;
        #pragma unroll 8
        for (int d = 0; d < DD; ++d)
            acc += pool[d] * w[d];       // pool[d]: same addr all lanes -> LDS broadcast
        out[b * LBL + threadIdx.x] = acc;
    }
}

extern "C" void kernel_launch(void* const* d_in, const int* in_sizes, int n_in,
                              void* d_out, int out_size, void* d_ws, size_t ws_size,
                              hipStream_t stream) {
    // Input order (setup_inputs): 0 find_contri, 1 contri, 2 code_output,
    // 3 lengths, 4 hidden, 5 W_attn, 6 b_attn, 7 W_pool.
    // energy is dead compute in the reference -> hidden/W_attn/b_attn unused.
    const float* code    = (const float*)d_in[2];
    const int*   lengths = (const int*)  d_in[3];
    const float* Wp      = (const float*)d_in[7];
    float*       out     = (float*)d_out;
    float*       partial = (float*)d_ws;

    // Workspace need: 64 * 128 * 256 * 4B = 8 MB (ws is ~1 GB).
    (void)ws_size;

    segmax_partial_kernel<<<BB * NCHUNK, 256, 0, stream>>>(code, lengths, partial);
    finalize_kernel<<<BB, 256, 0, stream>>>(partial, lengths, Wp, out);
}

// Round 3
// 32.296 us; speedup vs baseline: 1.4728x; 1.0450x over previous
//
#include <hip/hip_runtime.h>

// Problem constants (from reference): B=64, S=4096, D=256, LABELS=50
#define BB  64
#define SS  4096
#define DD  256
#define LBL 50

// 32 contiguous rows (32 KB) per chunk -> 128 chunks/batch, 8192 blocks.
// Only ~2048 blocks (8/CU) are resident; the rest are dispatched ON-DEMAND
// as blocks retire -> the HW dispatcher is the load balancer (round-0's
// fully-resident static grid had c = CU mod 32 pinned -> worst CU 2x mean).
// Chunks stay contiguous (round-1's stride-256 interleave killed locality).
#define CROWS  32
#define NCHUNK (SS / CROWS)      // 128

typedef float f4 __attribute__((ext_vector_type(4)));

static __device__ __forceinline__ f4 vmax4(f4 a, f4 b) {
    f4 r;
    r.x = fmaxf(a.x, b.x);
    r.y = fmaxf(a.y, b.y);
    r.z = fmaxf(a.z, b.z);
    r.w = fmaxf(a.w, b.w);
    return r;
}

// Kernel 1: per-(batch, 32-row chunk) partial max over valid rows.
// Block = 256 threads = 4 waves; wave w rows s0+w, s0+w+4, ... (8 when full).
// Lane holds a float4 column slice -> one wave covers a full 1KB row/iter.
// code is read ONCE -> nontemporal (no L2 allocate; keeps partial L2-hot).
__global__ __launch_bounds__(256) void segmax_partial_kernel(
    const float* __restrict__ code,      // [B, S, D]
    const int*   __restrict__ lengths,   // [B]
    float*       __restrict__ partial)   // [B * NCHUNK, D]
{
    int bid = blockIdx.x;
    int b   = bid >> 7;                  // bid / NCHUNK
    int c   = bid & (NCHUNK - 1);
    int len = lengths[b];
    int s0  = c * CROWS;
    if (s0 >= len) return;               // uniform per block: safe w.r.t. barrier
    int s1 = min(s0 + CROWS, len);

    int wave = threadIdx.x >> 6;
    int lane = threadIdx.x & 63;

    const f4* p = (const f4*)(code + (size_t)b * SS * DD)
                + (size_t)(s0 + wave) * (DD / 4) + lane;
    const float neg = -INFINITY;
    f4 m = (f4){neg, neg, neg, neg};

    if (s1 - s0 == CROWS) {
        // Full chunk: 8 rows/wave, all loads issued before reducing (MLP=8).
        f4 v0 = __builtin_nontemporal_load(p + 0 * 256);
        f4 v1 = __builtin_nontemporal_load(p + 1 * 256);
        f4 v2 = __builtin_nontemporal_load(p + 2 * 256);
        f4 v3 = __builtin_nontemporal_load(p + 3 * 256);
        f4 v4 = __builtin_nontemporal_load(p + 4 * 256);
        f4 v5 = __builtin_nontemporal_load(p + 5 * 256);
        f4 v6 = __builtin_nontemporal_load(p + 6 * 256);
        f4 v7 = __builtin_nontemporal_load(p + 7 * 256);
        m = vmax4(vmax4(vmax4(v0, v1), vmax4(v2, v3)),
                  vmax4(vmax4(v4, v5), vmax4(v6, v7)));
    } else {
        // Boundary chunk (len cuts inside): generic strided loop.
        for (int s = s0 + wave; s < s1; s += 4, p += 4 * (DD / 4))
            m = vmax4(m, __builtin_nontemporal_load(p));
    }

    __shared__ f4 red[4][64];
    red[wave][lane] = m;
    __syncthreads();

    if (threadIdx.x < 64) {
        f4 a = red[0][lane];
        #pragma unroll
        for (int w = 1; w < 4; ++w)
            a = vmax4(a, red[w][lane]);
        f4* dst = (f4*)(partial + (size_t)bid * DD);
        dst[lane] = a;                   // normal store: re-read by finalize
    }
}

// Kernel 2: per-batch final reduce over active partials + [256]x[256,50] dot.
// 1024 threads = 16 waves -> 4x the loads in flight vs the 256-thread
// version (the 64-block grid lights only 64 CUs; per-CU MLP is the lever:
// 16 waves x 4-deep x 1KB = 64KB outstanding -> ~1us for 128KB/CU).
__global__ __launch_bounds__(1024) void finalize_kernel(
    const float* __restrict__ partial,   // [B * NCHUNK, D]
    const int*   __restrict__ lengths,   // [B]
    const float* __restrict__ Wp,        // [LBL, D] row-major
    float*       __restrict__ out)       // [B, LBL]
{
    int b    = blockIdx.x;
    int wave = threadIdx.x >> 6;         // 0..15
    int lane = threadIdx.x & 63;
    int len  = lengths[b];
    int nact = (len + CROWS - 1) / CROWS;          // chunks that wrote a partial
    if (nact > NCHUNK) nact = NCHUNK;

    const f4* pb = (const f4*)partial + (size_t)b * NCHUNK * (DD / 4) + lane;
    const float neg = -INFINITY;
    f4 m = (f4){neg, neg, neg, neg};

    int c = wave;
    for (; c + 48 < nact; c += 64) {               // 4 independent loads in flight
        f4 a0 = __builtin_nontemporal_load(pb + (size_t)(c     ) * (DD / 4));
        f4 a1 = __builtin_nontemporal_load(pb + (size_t)(c + 16) * (DD / 4));
        f4 a2 = __builtin_nontemporal_load(pb + (size_t)(c + 32) * (DD / 4));
        f4 a3 = __builtin_nontemporal_load(pb + (size_t)(c + 48) * (DD / 4));
        m = vmax4(m, vmax4(vmax4(a0, a1), vmax4(a2, a3)));
    }
    for (; c < nact; c += 16)
        m = vmax4(m, __builtin_nontemporal_load(pb + (size_t)c * (DD / 4)));

    __shared__ f4 red[16][64];
    __shared__ float pool[DD];
    red[wave][lane] = m;
    __syncthreads();

    if (threadIdx.x < 64) {
        f4 a = red[0][lane];
        #pragma unroll
        for (int w = 1; w < 16; ++w)
            a = vmax4(a, red[w][lane]);
        ((f4*)pool)[lane] = a;
    }
    __syncthreads();

    if (threadIdx.x < LBL) {
        float acc = 0.0f;
        const float* w = Wp + (size_t)threadIdx.x * DD;
        #pragma unroll 8
        for (int d = 0; d < DD; ++d)
            acc += pool[d] * w[d];       // pool[d]: same addr all lanes -> LDS broadcast
        out[b * LBL + threadIdx.x] = acc;
    }
}

extern "C" void kernel_launch(void* const* d_in, const int* in_sizes, int n_in,
                              void* d_out, int out_size, void* d_ws, size_t ws_size,
                              hipStream_t stream) {
    // Input order (setup_inputs): 0 find_contri, 1 contri, 2 code_output,
    // 3 lengths, 4 hidden, 5 W_attn, 6 b_attn, 7 W_pool.
    // energy is dead compute in the reference -> hidden/W_attn/b_attn unused.
    const float* code    = (const float*)d_in[2];
    const int*   lengths = (const int*)  d_in[3];
    const float* Wp      = (const float*)d_in[7];
    float*       out     = (float*)d_out;
    float*       partial = (float*)d_ws;

    // Workspace need: 64 * 128 * 256 * 4B = 8 MB (ws is ~1 GB).
    (void)ws_size;

    segmax_partial_kernel<<<BB * NCHUNK, 256, 0, stream>>>(code, lengths, partial);
    finalize_kernel<<<BB, 1024, 0, stream>>>(partial, lengths, Wp, out);
}